// Round 1
// baseline (1967.334 us; speedup 1.0000x reference)
//
#include <hip/hip_runtime.h>
#include <hip/hip_bf16.h>

// Problem constants
#define BATCH 4
#define IMG 224
#define CDIM 256
#define WS 7
#define NWIN 4096        // 4 * 32 * 32
#define NTOK 49
#define TTOK 200704      // NWIN * NTOK
#define HEADS 8
#define HD 32
#define SCALE 0.5f       // (HEADS//2)^-0.5 = 4^-0.5
#define LN_EPS 1e-5f

// ---------------------------------------------------------------------------
// K1: QKV projection GEMM. M=TTOK, N=768, K=256.
// A rows gathered via window partition; output scattered to [3][8][TTOK][32].
// Tile: BM=64, BN=64, BK=16, 256 threads, 4x4 micro-tile.
// ---------------------------------------------------------------------------
__global__ __launch_bounds__(256) void qkv_gemm(
    const float* __restrict__ x, const float* __restrict__ wqkv,
    const float* __restrict__ bqkv, float* __restrict__ qkvbuf) {
  int bid = blockIdx.x;
  int nt = bid % 12;        // N-tile fastest -> A tile L2 reuse across 12 blocks
  int mt = bid / 12;
  int m0 = mt * 64, bn0 = nt * 64;

  __shared__ float As[16][64];   // [k][m]
  __shared__ float Bs[16][64];   // [k][n]
  __shared__ int rowoff[64];

  int tid = threadIdx.x;
  if (tid < 64) {
    int t = m0 + tid;
    int w = t / 49, n = t % 49;
    int b = w >> 10, rem = w & 1023;
    int wh = rem >> 5, ww = rem & 31;
    int gh = wh * 7 + n / 7;
    int gw = ww * 7 + n % 7;
    rowoff[tid] = ((b * IMG + gh) * IMG + gw) * CDIM;
  }
  __syncthreads();

  float acc[4][4] = {};
  int ty = tid >> 4, tx = tid & 15;        // 16x16 thread grid
  int arow = tid >> 2, kseg = tid & 3;     // A staging
  int brow = tid >> 4, bcol = (tid & 15) * 4;
  int aoff = rowoff[arow];

  for (int k0 = 0; k0 < 256; k0 += 16) {
    float4 a = *(const float4*)(x + aoff + k0 + kseg * 4);
    float4 bv = *(const float4*)(wqkv + (size_t)(k0 + brow) * 768 + bn0 + bcol);
    As[kseg * 4 + 0][arow] = a.x;
    As[kseg * 4 + 1][arow] = a.y;
    As[kseg * 4 + 2][arow] = a.z;
    As[kseg * 4 + 3][arow] = a.w;
    *(float4*)&Bs[brow][bcol] = bv;
    __syncthreads();
#pragma unroll
    for (int kk = 0; kk < 16; ++kk) {
      float4 a4 = *(const float4*)&As[kk][ty * 4];
      float4 b4 = *(const float4*)&Bs[kk][tx * 4];
      float av[4] = {a4.x, a4.y, a4.z, a4.w};
      float bw[4] = {b4.x, b4.y, b4.z, b4.w};
#pragma unroll
      for (int i = 0; i < 4; ++i)
#pragma unroll
        for (int j = 0; j < 4; ++j) acc[i][j] = fmaf(av[i], bw[j], acc[i][j]);
    }
    __syncthreads();
  }

  // epilogue: add bias, scatter to [which][head][t][d]
  int colbase = bn0 + tx * 4;
  int which = colbase >> 8;
  int hh = (colbase & 255) >> 5;
  int d0 = colbase & 31;
  float4 bq = *(const float4*)(bqkv + colbase);
#pragma unroll
  for (int i = 0; i < 4; ++i) {
    int t = m0 + ty * 4 + i;
    float4 o;
    o.x = acc[i][0] + bq.x;
    o.y = acc[i][1] + bq.y;
    o.z = acc[i][2] + bq.z;
    o.w = acc[i][3] + bq.w;
    *(float4*)(qkvbuf + (((size_t)(which * 8 + hh) * TTOK + t) * HD + d0)) = o;
  }
}

// ---------------------------------------------------------------------------
// K2: attention. One wave per (window, head). Block = 2 waves = 128 threads.
// Lane i (<49) owns query row i: q, scores, softmax all in registers.
// K/V staged in LDS (broadcast reads), bias table slice staged per head.
// ---------------------------------------------------------------------------
__global__ __launch_bounds__(128) void attn_kernel(
    const float* __restrict__ qkvbuf, const float* __restrict__ bias_table,
    float* __restrict__ attn_out) {
  int bid = blockIdx.x;            // NWIN * 4
  int w = bid >> 2;
  int wid = threadIdx.x >> 6;
  int lane = threadIdx.x & 63;
  int h = ((bid & 3) << 1) | wid;

  __shared__ float ksh[2][NTOK * HD];
  __shared__ float vsh[2][NTOK * HD];
  __shared__ float bsh[2][169];

  const size_t base_q = ((size_t)(0 * 8 + h) * TTOK + (size_t)w * 49) * HD;
  const size_t base_k = ((size_t)(1 * 8 + h) * TTOK + (size_t)w * 49) * HD;
  const size_t base_v = ((size_t)(2 * 8 + h) * TTOK + (size_t)w * 49) * HD;

  // stage K, V (49*32 floats = 392 float4 each)
  const float4* kg = (const float4*)(qkvbuf + base_k);
  const float4* vg = (const float4*)(qkvbuf + base_v);
  float4* ks4 = (float4*)ksh[wid];
  float4* vs4 = (float4*)vsh[wid];
  for (int idx = lane; idx < 392; idx += 64) {
    ks4[idx] = kg[idx];
    vs4[idx] = vg[idx];
  }
  for (int idx = lane; idx < 169; idx += 64)
    bsh[wid][idx] = bias_table[idx * HEADS + h];

  float q[32];
  if (lane < 49) {
    const float4* qp = (const float4*)(qkvbuf + base_q + (size_t)lane * HD);
#pragma unroll
    for (int d4 = 0; d4 < 8; ++d4) {
      float4 v = qp[d4];
      q[d4 * 4 + 0] = v.x; q[d4 * 4 + 1] = v.y;
      q[d4 * 4 + 2] = v.z; q[d4 * 4 + 3] = v.w;
    }
  }
  __syncthreads();

  if (lane >= 49) return;

  int ri = lane / 7, ci = lane % 7;
  float p[49];
  float mmax = -1e30f;
#pragma unroll
  for (int j = 0; j < 49; ++j) {
    const float* kr = &ksh[wid][j * HD];
    float s0 = 0.f, s1 = 0.f, s2 = 0.f, s3 = 0.f;
#pragma unroll
    for (int d4 = 0; d4 < 8; ++d4) {
      float4 kv = *(const float4*)(kr + d4 * 4);
      s0 = fmaf(q[d4 * 4 + 0], kv.x, s0);
      s1 = fmaf(q[d4 * 4 + 1], kv.y, s1);
      s2 = fmaf(q[d4 * 4 + 2], kv.z, s2);
      s3 = fmaf(q[d4 * 4 + 3], kv.w, s3);
    }
    int rj = j / 7, cj = j % 7;
    float bias = bsh[wid][(ri - rj + 6) * 13 + (ci - cj + 6)];
    float s = (s0 + s1 + s2 + s3) * SCALE + bias;
    p[j] = s;
    mmax = fmaxf(mmax, s);
  }
  float sum = 0.f;
#pragma unroll
  for (int j = 0; j < 49; ++j) {
    p[j] = __expf(p[j] - mmax);
    sum += p[j];
  }
  float rinv = 1.0f / sum;

  float o[32] = {};
#pragma unroll
  for (int j = 0; j < 49; ++j) {
    const float* vr = &vsh[wid][j * HD];
    float pj = p[j];
#pragma unroll
    for (int d4 = 0; d4 < 8; ++d4) {
      float4 vv = *(const float4*)(vr + d4 * 4);
      o[d4 * 4 + 0] = fmaf(pj, vv.x, o[d4 * 4 + 0]);
      o[d4 * 4 + 1] = fmaf(pj, vv.y, o[d4 * 4 + 1]);
      o[d4 * 4 + 2] = fmaf(pj, vv.z, o[d4 * 4 + 2]);
      o[d4 * 4 + 3] = fmaf(pj, vv.w, o[d4 * 4 + 3]);
    }
  }

  float4* op = (float4*)(attn_out + ((size_t)(w * 49 + lane)) * CDIM + h * HD);
#pragma unroll
  for (int d4 = 0; d4 < 8; ++d4) {
    float4 ov;
    ov.x = o[d4 * 4 + 0] * rinv;
    ov.y = o[d4 * 4 + 1] * rinv;
    ov.z = o[d4 * 4 + 2] * rinv;
    ov.w = o[d4 * 4 + 3] * rinv;
    op[d4] = ov;
  }
}

// ---------------------------------------------------------------------------
// K3: out-projection GEMM + bias + residual + LayerNorm.
// M=TTOK, N=256 (full row per block), K=256. BM=16, 256 threads (4x64),
// 4x4 micro-tile. LN via wave shuffle reduce (each wave owns 4 rows).
// ---------------------------------------------------------------------------
__global__ __launch_bounds__(256) void out_ln_kernel(
    const float* __restrict__ attn_out, const float* __restrict__ wout,
    const float* __restrict__ bout, const float* __restrict__ x,
    const float* __restrict__ gamma, const float* __restrict__ beta,
    float* __restrict__ out) {
  int m0 = blockIdx.x * 16;
  int tid = threadIdx.x;
  int ty = tid >> 6, tx = tid & 63;   // 4 x 64

  __shared__ float As[16][16];        // [k][m]
  __shared__ float Bs[16][256];       // [k][n]
  __shared__ int rowoff[16];

  if (tid < 16) {
    int t = m0 + tid;
    int w = t / 49, n = t % 49;
    int b = w >> 10, rem = w & 1023;
    int wh = rem >> 5, ww = rem & 31;
    int gh = wh * 7 + n / 7;
    int gw = ww * 7 + n % 7;
    rowoff[tid] = ((b * IMG + gh) * IMG + gw) * CDIM;
  }
  __syncthreads();

  float acc[4][4] = {};
  for (int k0 = 0; k0 < 256; k0 += 16) {
    if (tid < 64) {
      int row = tid >> 2, ks = (tid & 3) * 4;
      float4 a = *(const float4*)(attn_out + (size_t)(m0 + row) * CDIM + k0 + ks);
      As[ks + 0][row] = a.x;
      As[ks + 1][row] = a.y;
      As[ks + 2][row] = a.z;
      As[ks + 3][row] = a.w;
    }
#pragma unroll
    for (int r = 0; r < 4; ++r) {
      int row = r * 4 + ty;
      int col = tx * 4;
      *(float4*)&Bs[row][col] = *(const float4*)(wout + (size_t)(k0 + row) * CDIM + col);
    }
    __syncthreads();
#pragma unroll
    for (int kk = 0; kk < 16; ++kk) {
      float4 a4 = *(const float4*)&As[kk][ty * 4];
      float4 b4 = *(const float4*)&Bs[kk][tx * 4];
      float av[4] = {a4.x, a4.y, a4.z, a4.w};
      float bw[4] = {b4.x, b4.y, b4.z, b4.w};
#pragma unroll
      for (int i = 0; i < 4; ++i)
#pragma unroll
        for (int j = 0; j < 4; ++j) acc[i][j] = fmaf(av[i], bw[j], acc[i][j]);
    }
    __syncthreads();
  }

  int col = tx * 4;
  float4 bo = *(const float4*)(bout + col);
  float4 gm = *(const float4*)(gamma + col);
  float4 bt = *(const float4*)(beta + col);

#pragma unroll
  for (int i = 0; i < 4; ++i) {
    int r = ty * 4 + i;
    int t = m0 + r;
    float4 resid = *(const float4*)(x + rowoff[r] + col);
    float v0 = acc[i][0] + bo.x + resid.x;
    float v1 = acc[i][1] + bo.y + resid.y;
    float v2 = acc[i][2] + bo.z + resid.z;
    float v3 = acc[i][3] + bo.w + resid.w;
    float s1 = v0 + v1 + v2 + v3;
    float s2 = v0 * v0 + v1 * v1 + v2 * v2 + v3 * v3;
#pragma unroll
    for (int off = 32; off > 0; off >>= 1) {
      s1 += __shfl_xor(s1, off);
      s2 += __shfl_xor(s2, off);
    }
    float mean = s1 * (1.0f / 256.0f);
    float var = s2 * (1.0f / 256.0f) - mean * mean;
    float rstd = rsqrtf(var + LN_EPS);
    float4 ov;
    ov.x = (v0 - mean) * rstd * gm.x + bt.x;
    ov.y = (v1 - mean) * rstd * gm.y + bt.y;
    ov.z = (v2 - mean) * rstd * gm.z + bt.z;
    ov.w = (v3 - mean) * rstd * gm.w + bt.w;
    *(float4*)(out + (size_t)t * CDIM + col) = ov;
  }
}

extern "C" void kernel_launch(void* const* d_in, const int* in_sizes, int n_in,
                              void* d_out, int out_size, void* d_ws, size_t ws_size,
                              hipStream_t stream) {
  const float* x     = (const float*)d_in[0];
  const float* wqkv  = (const float*)d_in[1];
  const float* bqkv  = (const float*)d_in[2];
  const float* btab  = (const float*)d_in[3];
  const float* wout  = (const float*)d_in[4];
  const float* bout  = (const float*)d_in[5];
  const float* gamma = (const float*)d_in[6];
  const float* beta  = (const float*)d_in[7];
  float* out = (float*)d_out;

  float* qkvbuf  = (float*)d_ws;                              // [3][8][TTOK][32] = 616 MB
  float* attnbuf = qkvbuf + (size_t)3 * HEADS * TTOK * HD;    // [TTOK][256]      = 205 MB

  qkv_gemm<<<dim3(12 * (TTOK / 64)), dim3(256), 0, stream>>>(x, wqkv, bqkv, qkvbuf);
  attn_kernel<<<dim3(NWIN * 4), dim3(128), 0, stream>>>(qkvbuf, btab, attnbuf);
  out_ln_kernel<<<dim3(TTOK / 16), dim3(256), 0, stream>>>(attnbuf, wout, bout, x,
                                                           gamma, beta, out);
}

// Round 2
// 1837.561 us; speedup vs baseline: 1.0706x; 1.0706x over previous
//
#include <hip/hip_runtime.h>
#include <hip/hip_bf16.h>

#define BATCH 4
#define IMG 224
#define CDIM 256
#define WS 7
#define NWIN 4096
#define NTOK 49
#define TTOK 200704
#define HEADS 8
#define HD 32
#define SCALE 0.5f
#define LN_EPS 1e-5f

typedef __attribute__((ext_vector_type(8))) short short8v;
typedef __attribute__((ext_vector_type(4))) float f32x4;
typedef unsigned short u16;

__device__ __forceinline__ u16 f2bf(float f) {
  __hip_bfloat16 h = __float2bfloat16(f);
  return *reinterpret_cast<u16*>(&h);
}

__device__ __forceinline__ void gld_lds16(const void* g, void* l) {
  __builtin_amdgcn_global_load_lds(
      (const __attribute__((address_space(1))) unsigned int*)g,
      (__attribute__((address_space(3))) unsigned int*)l, 16, 0, 0);
}

// ---------------------------------------------------------------------------
// K0a: gather window-partitioned x and convert to bf16: xb[TTOK][256]
// ---------------------------------------------------------------------------
__global__ __launch_bounds__(256) void pack_x(const float* __restrict__ x,
                                              u16* __restrict__ xb) {
  const int NCH = TTOK * 32;  // 8-elem chunks
  for (int id = blockIdx.x * 256 + threadIdx.x; id < NCH; id += 2048 * 256) {
    int t = id >> 5;
    int cc = (id & 31) << 3;
    int wq = t / 49, n = t - wq * 49;
    int b = wq >> 10, rem = wq & 1023;
    int gh = (rem >> 5) * 7 + n / 7;
    int gw = (rem & 31) * 7 + n % 7;
    const float* src = x + (((size_t)b * IMG + gh) * IMG + gw) * CDIM + cc;
    float4 f0 = *(const float4*)src;
    float4 f1 = *(const float4*)(src + 4);
    union { u16 us[8]; uint4 v; } pk;
    pk.us[0] = f2bf(f0.x); pk.us[1] = f2bf(f0.y);
    pk.us[2] = f2bf(f0.z); pk.us[3] = f2bf(f0.w);
    pk.us[4] = f2bf(f1.x); pk.us[5] = f2bf(f1.y);
    pk.us[6] = f2bf(f1.z); pk.us[7] = f2bf(f1.w);
    *(uint4*)(xb + (size_t)id * 8) = pk.v;
  }
}

// ---------------------------------------------------------------------------
// K0b: transpose+convert weights to N-major bf16 (so MFMA B-frags are
// k-contiguous): wqkvT[n][k], woutT[n][k]
// ---------------------------------------------------------------------------
__global__ __launch_bounds__(256) void pack_w(const float* __restrict__ wqkv,
                                              const float* __restrict__ wout,
                                              u16* __restrict__ wqkvT,
                                              u16* __restrict__ woutT) {
  int id = blockIdx.x * 256 + threadIdx.x;  // 262144
  if (id < 196608) {
    int nn = id >> 8, k = id & 255;
    wqkvT[id] = f2bf(wqkv[(size_t)k * 768 + nn]);
  } else {
    int id2 = id - 196608;
    int nn = id2 >> 8, k = id2 & 255;
    woutT[id2] = f2bf(wout[(size_t)k * 256 + nn]);
  }
}

// ---------------------------------------------------------------------------
// K1: QKV GEMM, bf16 MFMA. M=TTOK, N=768, K=256. 128x128 tile, BK=32,
// 4 waves (2x2), fragment-ordered LDS subtiles, global_load_lds x16,
// double-buffered. Output scattered fp32 to [3][8][TTOK][32].
// ---------------------------------------------------------------------------
__global__ __launch_bounds__(256) void qkv_gemm(const u16* __restrict__ xb,
                                                const u16* __restrict__ wqkvT,
                                                const float* __restrict__ bqkv,
                                                float* __restrict__ qkvbuf) {
  __shared__ __align__(16) short As[2][4096];  // 8 subtiles x 64 lanes x 8 bf16
  __shared__ __align__(16) short Bs[2][4096];

  int tid = threadIdx.x;
  int lane = tid & 63, wid = tid >> 6;
  int wm = wid >> 1, wn = wid & 1;
  int mt = blockIdx.x / 6, nt = blockIdx.x % 6;
  int m0 = mt * 128, n0 = nt * 128;

  f32x4 zero = {0.f, 0.f, 0.f, 0.f};
  f32x4 acc[4][4];
#pragma unroll
  for (int m = 0; m < 4; ++m)
#pragma unroll
    for (int n = 0; n < 4; ++n) acc[m][n] = zero;

#define STAGE_K1(buf, k0)                                                \
  {                                                                      \
    _Pragma("unroll") for (int i = 0; i < 2; ++i) {                      \
      int c = i * 256 + tid;                                             \
      int l6 = c & 63;                                                   \
      int rr = ((c >> 6) << 4) + (l6 & 15);                              \
      int kk = (k0) + ((l6 >> 4) << 3);                                  \
      gld_lds16(xb + (size_t)(m0 + rr) * 256 + kk, &As[buf][c * 8]);     \
      gld_lds16(wqkvT + (size_t)(n0 + rr) * 256 + kk, &Bs[buf][c * 8]);  \
    }                                                                    \
  }

  STAGE_K1(0, 0);
  __syncthreads();

  int buf = 0;
  for (int ks = 0; ks < 8; ++ks) {
    if (ks < 7) STAGE_K1(buf ^ 1, (ks + 1) * 32);
    short8v af[4], bfv[4];
#pragma unroll
    for (int m = 0; m < 4; ++m)
      af[m] = *(const short8v*)&As[buf][((wm * 4 + m) * 64 + lane) * 8];
#pragma unroll
    for (int n = 0; n < 4; ++n)
      bfv[n] = *(const short8v*)&Bs[buf][((wn * 4 + n) * 64 + lane) * 8];
#pragma unroll
    for (int m = 0; m < 4; ++m)
#pragma unroll
      for (int n = 0; n < 4; ++n)
        acc[m][n] = __builtin_amdgcn_mfma_f32_16x16x32_bf16(af[m], bfv[n],
                                                            acc[m][n], 0, 0, 0);
    __syncthreads();
    buf ^= 1;
  }

  // epilogue: bias + scatter fp32 to [which][head][t][d]
  int fr = lane & 15, fq = lane >> 4;
#pragma unroll
  for (int n = 0; n < 4; ++n) {
    int c = n0 + wn * 64 + n * 16 + fr;
    float bias = bqkv[c];
    size_t plane = (size_t)((c >> 8) * 8 + ((c >> 5) & 7)) * (size_t)TTOK;
    int d = c & 31;
#pragma unroll
    for (int m = 0; m < 4; ++m) {
      int trow = m0 + wm * 64 + m * 16 + fq * 4;
#pragma unroll
      for (int r = 0; r < 4; ++r)
        qkvbuf[(plane + trow + r) * 32 + d] = acc[m][n][r] + bias;
    }
  }
}

// ---------------------------------------------------------------------------
// K2: attention. 4 waves/block, one (window,head) per wave. Lane<49 owns a
// query row; K/V read directly from global (each row read once, lane-
// broadcast, L1-served). Writes attn_out bf16 [TTOK][256].
// ---------------------------------------------------------------------------
__global__ __launch_bounds__(256) void attn_kernel(
    const float* __restrict__ qkvbuf, const float* __restrict__ bias_table,
    u16* __restrict__ attnb) {
  int bid = blockIdx.x;  // NWIN*2
  int w = bid >> 1;
  int wid = threadIdx.x >> 6, lane = threadIdx.x & 63;
  int h = ((bid & 1) << 2) | wid;

  __shared__ float bsh[4][169];
  for (int idx = lane; idx < 169; idx += 64)
    bsh[wid][idx] = bias_table[idx * HEADS + h];

  const size_t wbase = (size_t)w * 49 * 32;
  const float* qp = qkvbuf + (size_t)h * TTOK * 32 + wbase;
  const float* kp = qkvbuf + (size_t)(8 + h) * TTOK * 32 + wbase;
  const float* vp = qkvbuf + (size_t)(16 + h) * TTOK * 32 + wbase;

  float q[32];
  if (lane < 49) {
    const float4* q4 = (const float4*)(qp + (size_t)lane * 32);
#pragma unroll
    for (int d4 = 0; d4 < 8; ++d4) {
      float4 v = q4[d4];
      q[d4 * 4 + 0] = v.x; q[d4 * 4 + 1] = v.y;
      q[d4 * 4 + 2] = v.z; q[d4 * 4 + 3] = v.w;
    }
  }
  __syncthreads();
  if (lane >= 49) return;

  int ri = lane / 7, ci = lane % 7;
  float p[49];
  float mmax = -1e30f;
#pragma unroll
  for (int j = 0; j < 49; ++j) {
    const float4* kr = (const float4*)(kp + j * 32);
    float s0 = 0.f, s1 = 0.f, s2 = 0.f, s3 = 0.f;
#pragma unroll
    for (int d4 = 0; d4 < 8; ++d4) {
      float4 kv = kr[d4];
      s0 = fmaf(q[d4 * 4 + 0], kv.x, s0);
      s1 = fmaf(q[d4 * 4 + 1], kv.y, s1);
      s2 = fmaf(q[d4 * 4 + 2], kv.z, s2);
      s3 = fmaf(q[d4 * 4 + 3], kv.w, s3);
    }
    int rj = j / 7, cj = j % 7;
    float s = (s0 + s1 + s2 + s3) * SCALE + bsh[wid][(ri - rj + 6) * 13 + (ci - cj + 6)];
    p[j] = s;
    mmax = fmaxf(mmax, s);
  }
  float sum = 0.f;
#pragma unroll
  for (int j = 0; j < 49; ++j) {
    p[j] = __expf(p[j] - mmax);
    sum += p[j];
  }
  float rinv = 1.0f / sum;

  float o[32] = {};
#pragma unroll
  for (int j = 0; j < 49; ++j) {
    const float4* vr = (const float4*)(vp + j * 32);
    float pj = p[j];
#pragma unroll
    for (int d4 = 0; d4 < 8; ++d4) {
      float4 vv = vr[d4];
      o[d4 * 4 + 0] = fmaf(pj, vv.x, o[d4 * 4 + 0]);
      o[d4 * 4 + 1] = fmaf(pj, vv.y, o[d4 * 4 + 1]);
      o[d4 * 4 + 2] = fmaf(pj, vv.z, o[d4 * 4 + 2]);
      o[d4 * 4 + 3] = fmaf(pj, vv.w, o[d4 * 4 + 3]);
    }
  }

  size_t dst = (size_t)(w * 49 + lane) * 256 + h * 32;
#pragma unroll
  for (int g = 0; g < 4; ++g) {
    union { u16 us[8]; uint4 v; } pk;
#pragma unroll
    for (int e = 0; e < 8; ++e) pk.us[e] = f2bf(o[g * 8 + e] * rinv);
    *(uint4*)(attnb + dst + g * 8) = pk.v;
  }
}

// ---------------------------------------------------------------------------
// K3: out-proj MFMA + bias + residual + LayerNorm. M=TTOK, N=256(full),
// K=256. BM=128, BK=32, 8 waves (2x4). Cross-wave LN stats via LDS atomics.
// ---------------------------------------------------------------------------
__global__ __launch_bounds__(512) void out_ln_kernel(
    const u16* __restrict__ attnb, const u16* __restrict__ woutT,
    const float* __restrict__ bout, const float* __restrict__ x,
    const float* __restrict__ gamma, const float* __restrict__ beta,
    float* __restrict__ out) {
  __shared__ __align__(16) short As[2][4096];   // 8 subtiles
  __shared__ __align__(16) short Bs[2][8192];   // 16 subtiles
  __shared__ float ls1[128], ls2[128];
  __shared__ int rowoff_s[128];

  int tid = threadIdx.x;
  int lane = tid & 63, wid = tid >> 6;
  int wm = wid >> 2, wn = wid & 3;
  int m0 = blockIdx.x * 128;

  if (tid < 128) {
    ls1[tid] = 0.f;
    ls2[tid] = 0.f;
    int t = m0 + tid;
    int wq = t / 49, n = t - wq * 49;
    int b = wq >> 10, rem = wq & 1023;
    int gh = (rem >> 5) * 7 + n / 7;
    int gw = (rem & 31) * 7 + n % 7;
    rowoff_s[tid] = ((b * IMG + gh) * IMG + gw) * CDIM;
  }

  f32x4 zero = {0.f, 0.f, 0.f, 0.f};
  f32x4 acc[4][4];
#pragma unroll
  for (int m = 0; m < 4; ++m)
#pragma unroll
    for (int n = 0; n < 4; ++n) acc[m][n] = zero;

#define STAGE_K3(buf, k0)                                                 \
  {                                                                       \
    {                                                                     \
      int c = tid;                                                        \
      int l6 = c & 63;                                                    \
      int rr = ((c >> 6) << 4) + (l6 & 15);                               \
      int kk = (k0) + ((l6 >> 4) << 3);                                   \
      gld_lds16(attnb + (size_t)(m0 + rr) * 256 + kk, &As[buf][c * 8]);   \
    }                                                                     \
    _Pragma("unroll") for (int i = 0; i < 2; ++i) {                       \
      int c = i * 512 + tid;                                              \
      int l6 = c & 63;                                                    \
      int cc = ((c >> 6) << 4) + (l6 & 15);                               \
      int kk = (k0) + ((l6 >> 4) << 3);                                   \
      gld_lds16(woutT + (size_t)cc * 256 + kk, &Bs[buf][c * 8]);          \
    }                                                                     \
  }

  STAGE_K3(0, 0);
  __syncthreads();

  int buf = 0;
  for (int ks = 0; ks < 8; ++ks) {
    if (ks < 7) STAGE_K3(buf ^ 1, (ks + 1) * 32);
    short8v af[4], bfv[4];
#pragma unroll
    for (int m = 0; m < 4; ++m)
      af[m] = *(const short8v*)&As[buf][((wm * 4 + m) * 64 + lane) * 8];
#pragma unroll
    for (int n = 0; n < 4; ++n)
      bfv[n] = *(const short8v*)&Bs[buf][((wn * 4 + n) * 64 + lane) * 8];
#pragma unroll
    for (int m = 0; m < 4; ++m)
#pragma unroll
      for (int n = 0; n < 4; ++n)
        acc[m][n] = __builtin_amdgcn_mfma_f32_16x16x32_bf16(af[m], bfv[n],
                                                            acc[m][n], 0, 0, 0);
    __syncthreads();
    buf ^= 1;
  }

  // epilogue: v = acc + bias + residual; LN stats; normalize; store
  int fr = lane & 15, fq = lane >> 4;
#pragma unroll
  for (int m = 0; m < 4; ++m) {
#pragma unroll
    for (int r = 0; r < 4; ++r) {
      int lrow = wm * 64 + m * 16 + fq * 4 + r;
      const float* xr = x + rowoff_s[lrow];
      float s1 = 0.f, s2 = 0.f;
#pragma unroll
      for (int n = 0; n < 4; ++n) {
        int c = wn * 64 + n * 16 + fr;
        float v = acc[m][n][r] + bout[c] + xr[c];
        acc[m][n][r] = v;
        s1 += v;
        s2 += v * v;
      }
#pragma unroll
      for (int off = 1; off < 16; off <<= 1) {
        s1 += __shfl_xor(s1, off);
        s2 += __shfl_xor(s2, off);
      }
      if (fr == 0) {
        atomicAdd(&ls1[lrow], s1);
        atomicAdd(&ls2[lrow], s2);
      }
    }
  }
  __syncthreads();

#pragma unroll
  for (int m = 0; m < 4; ++m) {
#pragma unroll
    for (int r = 0; r < 4; ++r) {
      int lrow = wm * 64 + m * 16 + fq * 4 + r;
      float mean = ls1[lrow] * (1.0f / 256.0f);
      float var = ls2[lrow] * (1.0f / 256.0f) - mean * mean;
      float rstd = rsqrtf(var + LN_EPS);
      size_t orow = (size_t)(m0 + lrow) * 256;
#pragma unroll
      for (int n = 0; n < 4; ++n) {
        int c = wn * 64 + n * 16 + fr;
        out[orow + c] = (acc[m][n][r] - mean) * rstd * gamma[c] + beta[c];
      }
    }
  }
}

extern "C" void kernel_launch(void* const* d_in, const int* in_sizes, int n_in,
                              void* d_out, int out_size, void* d_ws, size_t ws_size,
                              hipStream_t stream) {
  const float* x     = (const float*)d_in[0];
  const float* wqkv  = (const float*)d_in[1];
  const float* bqkv  = (const float*)d_in[2];
  const float* btab  = (const float*)d_in[3];
  const float* wout  = (const float*)d_in[4];
  const float* bout  = (const float*)d_in[5];
  const float* gamma = (const float*)d_in[6];
  const float* beta  = (const float*)d_in[7];
  float* out = (float*)d_out;

  float* qkvbuf = (float*)d_ws;                                  // 616.6 MB fp32
  u16* xb       = (u16*)(qkvbuf + (size_t)24 * TTOK * 32);       // 102.8 MB bf16
  u16* attnb    = xb;                                            // reused after K1
  u16* wqkvT    = xb + (size_t)TTOK * 256;                       // 768x256 bf16
  u16* woutT    = wqkvT + 196608;                                // 256x256 bf16

  pack_x<<<2048, 256, 0, stream>>>(x, xb);
  pack_w<<<1024, 256, 0, stream>>>(wqkv, wout, wqkvT, woutT);
  qkv_gemm<<<(TTOK / 128) * 6, 256, 0, stream>>>(xb, wqkvT, bqkv, qkvbuf);
  attn_kernel<<<NWIN * 2, 256, 0, stream>>>(qkvbuf, btab, attnb);
  out_ln_kernel<<<TTOK / 128, 512, 0, stream>>>(attnb, woutT, bout, x, gamma,
                                                beta, out);
}

// Round 3
// 924.756 us; speedup vs baseline: 2.1274x; 1.9871x over previous
//
#include <hip/hip_runtime.h>
#include <hip/hip_bf16.h>

#define BATCH 4
#define IMG 224
#define CDIM 256
#define WS 7
#define NWIN 4096
#define NTOK 49
#define TTOK 200704
#define HEADS 8
#define HD 32
#define SCALE 0.5f
#define LN_EPS 1e-5f

typedef __attribute__((ext_vector_type(8))) short short8v;
typedef __attribute__((ext_vector_type(4))) float f32x4;
typedef unsigned short u16;

__device__ __forceinline__ u16 f2bf(float f) {
  __hip_bfloat16 h = __float2bfloat16(f);
  return *reinterpret_cast<u16*>(&h);
}

__device__ __forceinline__ void gld_lds16(const void* g, void* l) {
  __builtin_amdgcn_global_load_lds(
      (const __attribute__((address_space(1))) unsigned int*)g,
      (__attribute__((address_space(3))) unsigned int*)l, 16, 0, 0);
}

// ---------------------------------------------------------------------------
// K0a: gather window-partitioned x and convert to bf16: xb[TTOK][256]
// ---------------------------------------------------------------------------
__global__ __launch_bounds__(256) void pack_x(const float* __restrict__ x,
                                              u16* __restrict__ xb) {
  const int NCH = TTOK * 32;  // 8-elem chunks
  for (int id = blockIdx.x * 256 + threadIdx.x; id < NCH; id += 2048 * 256) {
    int t = id >> 5;
    int cc = (id & 31) << 3;
    int wq = t / 49, n = t - wq * 49;
    int b = wq >> 10, rem = wq & 1023;
    int gh = (rem >> 5) * 7 + n / 7;
    int gw = (rem & 31) * 7 + n % 7;
    const float* src = x + (((size_t)b * IMG + gh) * IMG + gw) * CDIM + cc;
    float4 f0 = *(const float4*)src;
    float4 f1 = *(const float4*)(src + 4);
    union { u16 us[8]; uint4 v; } pk;
    pk.us[0] = f2bf(f0.x); pk.us[1] = f2bf(f0.y);
    pk.us[2] = f2bf(f0.z); pk.us[3] = f2bf(f0.w);
    pk.us[4] = f2bf(f1.x); pk.us[5] = f2bf(f1.y);
    pk.us[6] = f2bf(f1.z); pk.us[7] = f2bf(f1.w);
    *(uint4*)(xb + (size_t)id * 8) = pk.v;
  }
}

// ---------------------------------------------------------------------------
// K0b: transpose+convert weights to N-major bf16: wqkvT[n][k], woutT[n][k]
// ---------------------------------------------------------------------------
__global__ __launch_bounds__(256) void pack_w(const float* __restrict__ wqkv,
                                              const float* __restrict__ wout,
                                              u16* __restrict__ wqkvT,
                                              u16* __restrict__ woutT) {
  int id = blockIdx.x * 256 + threadIdx.x;  // 262144
  if (id < 196608) {
    int nn = id >> 8, k = id & 255;
    wqkvT[id] = f2bf(wqkv[(size_t)k * 768 + nn]);
  } else {
    int id2 = id - 196608;
    int nn = id2 >> 8, k = id2 & 255;
    woutT[id2] = f2bf(wout[(size_t)k * 256 + nn]);
  }
}

// ---------------------------------------------------------------------------
// K1: QKV GEMM, bf16 MFMA, 128x128 tile, BK=32, double-buffered
// global_load_lds. Output: bf16, planes [which][head][t][32].
// ---------------------------------------------------------------------------
__global__ __launch_bounds__(256) void qkv_gemm(const u16* __restrict__ xb,
                                                const u16* __restrict__ wqkvT,
                                                const float* __restrict__ bqkv,
                                                u16* __restrict__ qkvb) {
  __shared__ __align__(16) short As[2][4096];
  __shared__ __align__(16) short Bs[2][4096];

  int tid = threadIdx.x;
  int lane = tid & 63, wid = tid >> 6;
  int wm = wid >> 1, wn = wid & 1;
  int mt = blockIdx.x / 6, nt = blockIdx.x % 6;
  int m0 = mt * 128, n0 = nt * 128;

  f32x4 zero = {0.f, 0.f, 0.f, 0.f};
  f32x4 acc[4][4];
#pragma unroll
  for (int m = 0; m < 4; ++m)
#pragma unroll
    for (int n = 0; n < 4; ++n) acc[m][n] = zero;

#define STAGE_K1(buf, k0)                                                \
  {                                                                      \
    _Pragma("unroll") for (int i = 0; i < 2; ++i) {                      \
      int c = i * 256 + tid;                                             \
      int l6 = c & 63;                                                   \
      int rr = ((c >> 6) << 4) + (l6 & 15);                              \
      int kk = (k0) + ((l6 >> 4) << 3);                                  \
      gld_lds16(xb + (size_t)(m0 + rr) * 256 + kk, &As[buf][c * 8]);     \
      gld_lds16(wqkvT + (size_t)(n0 + rr) * 256 + kk, &Bs[buf][c * 8]);  \
    }                                                                    \
  }

  STAGE_K1(0, 0);
  __syncthreads();

  int buf = 0;
  for (int ks = 0; ks < 8; ++ks) {
    if (ks < 7) STAGE_K1(buf ^ 1, (ks + 1) * 32);
    short8v af[4], bfv[4];
#pragma unroll
    for (int m = 0; m < 4; ++m)
      af[m] = *(const short8v*)&As[buf][((wm * 4 + m) * 64 + lane) * 8];
#pragma unroll
    for (int n = 0; n < 4; ++n)
      bfv[n] = *(const short8v*)&Bs[buf][((wn * 4 + n) * 64 + lane) * 8];
#pragma unroll
    for (int m = 0; m < 4; ++m)
#pragma unroll
      for (int n = 0; n < 4; ++n)
        acc[m][n] = __builtin_amdgcn_mfma_f32_16x16x32_bf16(af[m], bfv[n],
                                                            acc[m][n], 0, 0, 0);
    __syncthreads();
    buf ^= 1;
  }

  // epilogue: bias + bf16 scatter to [which*8+head][t][d]
  int fr = lane & 15, fq = lane >> 4;
#pragma unroll
  for (int n = 0; n < 4; ++n) {
    int c = n0 + wn * 64 + n * 16 + fr;
    float bias = bqkv[c];
    u16* plane = qkvb + (size_t)((c >> 8) * 8 + ((c >> 5) & 7)) * TTOK * 32;
    int d = c & 31;
#pragma unroll
    for (int m = 0; m < 4; ++m) {
      int t0 = m0 + wm * 64 + m * 16 + fq * 4;
#pragma unroll
      for (int r = 0; r < 4; ++r)
        plane[(size_t)(t0 + r) * 32 + d] = f2bf(acc[m][n][r] + bias);
    }
  }
}

// ---------------------------------------------------------------------------
// K2: MFMA attention. One wave per (window, head); 4 waves/block.
// Q/K frags direct from global; V transposed into LDS; P via LDS (swizzled).
// Cols >= 49 masked to -1e30. Writes attnb bf16 [t][256].
// ---------------------------------------------------------------------------
__global__ __launch_bounds__(256) void attn_kernel(
    const u16* __restrict__ qkvb, const float* __restrict__ bias_table,
    u16* __restrict__ attnb) {
  __shared__ u16 Pl[4][4096];       // 64x64 bf16, XOR-swizzled
  __shared__ u16 Vl[4][32 * 72];    // V^T: [d][k], stride 72
  __shared__ float bsh[4][169];

  int bid = blockIdx.x;  // NWIN*2
  int w = bid >> 1;
  int wid = threadIdx.x >> 6, lane = threadIdx.x & 63;
  int h = ((bid & 1) << 2) | wid;
  int cl = lane & 15, cg = lane >> 4;

  for (int i = lane; i < 169; i += 64)
    bsh[wid][i] = bias_table[i * HEADS + h];

  const size_t wbase = (size_t)w * 49 * 32;
  const u16* qp = qkvb + (size_t)h * TTOK * 32 + wbase;
  const u16* kp = qkvb + (size_t)(8 + h) * TTOK * 32 + wbase;
  const u16* vp = qkvb + (size_t)(16 + h) * TTOK * 32 + wbase;

  // Q/K fragments (A-frag layout: row = lane&15, k = (lane>>4)*8 + j)
  short8v qf[4], kf[4];
#pragma unroll
  for (int mt = 0; mt < 4; ++mt) {
    int off = (mt * 16 + cl) * 32 + cg * 8;
    qf[mt] = *(const short8v*)(qp + off);
    kf[mt] = *(const short8v*)(kp + off);
  }

  // stage V transposed into LDS: Vl[d][k], zero-fill k >= 49
  short8v vz = {0, 0, 0, 0, 0, 0, 0, 0};
#pragma unroll
  for (int pass = 0; pass < 4; ++pass) {
    int cidx = pass * 64 + lane;
    int t = cidx >> 2, dc = (cidx & 3) * 8;
    short8v vv = (t < 49) ? *(const short8v*)(vp + t * 32 + dc) : vz;
#pragma unroll
    for (int j = 0; j < 8; ++j) Vl[wid][(dc + j) * 72 + t] = vv[j];
  }

  // S = Q K^T  (16 MFMAs, K=32 = full head dim)
  f32x4 zero4 = {0.f, 0.f, 0.f, 0.f};
  f32x4 s[4][4];
#pragma unroll
  for (int mt = 0; mt < 4; ++mt)
#pragma unroll
    for (int nt = 0; nt < 4; ++nt)
      s[mt][nt] = __builtin_amdgcn_mfma_f32_16x16x32_bf16(qf[mt], kf[nt],
                                                          zero4, 0, 0, 0);

  // key-side bias decomposition (col = nt*16 + cl)
  int kr7[4], kc7[4];
#pragma unroll
  for (int nt = 0; nt < 4; ++nt) {
    int col = nt * 16 + cl;
    kr7[nt] = (col * 9363) >> 16;
    kc7[nt] = col - kr7[nt] * 7;
  }

  // bias + scale + mask, then softmax per row (C-layout: row=(cg)*4+r)
  f32x4 rinv[4];
#pragma unroll
  for (int mt = 0; mt < 4; ++mt) {
#pragma unroll
    for (int r = 0; r < 4; ++r) {
      int row = mt * 16 + cg * 4 + r;
      int qr = (row * 9363) >> 16;
      int qc = row - qr * 7;
      float sv[4];
#pragma unroll
      for (int nt = 0; nt < 4; ++nt) {
        int col = nt * 16 + cl;
        if (col < 49) {
          int idx = (qr - kr7[nt] + 6) * 13 + (qc - kc7[nt] + 6);
          sv[nt] = s[mt][nt][r] * SCALE + bsh[wid][idx];
        } else {
          sv[nt] = -1e30f;
        }
      }
      float m = fmaxf(fmaxf(sv[0], sv[1]), fmaxf(sv[2], sv[3]));
#pragma unroll
      for (int msk = 1; msk < 16; msk <<= 1) m = fmaxf(m, __shfl_xor(m, msk));
      float sum = 0.f;
#pragma unroll
      for (int nt = 0; nt < 4; ++nt) {
        float p = __expf(sv[nt] - m);
        s[mt][nt][r] = p;
        sum += p;
      }
#pragma unroll
      for (int msk = 1; msk < 16; msk <<= 1) sum += __shfl_xor(sum, msk);
      rinv[mt][r] = 1.0f / sum;
    }
  }

  // write P (bf16) to LDS, XOR-swizzled on element index
#pragma unroll
  for (int mt = 0; mt < 4; ++mt)
#pragma unroll
    for (int r = 0; r < 4; ++r) {
      int row = mt * 16 + cg * 4 + r;
      int swz = (row & 7) << 3;
#pragma unroll
      for (int nt = 0; nt < 4; ++nt) {
        int col = nt * 16 + cl;
        Pl[wid][(row * 64 + col) ^ swz] = f2bf(s[mt][nt][r]);
      }
    }

  // O = P V   (A = P from LDS, B = V^T rows from LDS)
  f32x4 o[4][2];
#pragma unroll
  for (int mt = 0; mt < 4; ++mt)
#pragma unroll
    for (int nt2 = 0; nt2 < 2; ++nt2) o[mt][nt2] = zero4;

#pragma unroll
  for (int kt = 0; kt < 2; ++kt) {
    short8v vfr[2];
#pragma unroll
    for (int nt2 = 0; nt2 < 2; ++nt2)
      vfr[nt2] = *(const short8v*)&Vl[wid][(nt2 * 16 + cl) * 72 + kt * 32 + cg * 8];
#pragma unroll
    for (int mt = 0; mt < 4; ++mt) {
      int row = mt * 16 + cl;
      short8v pa = *(const short8v*)
          &Pl[wid][(row * 64 + kt * 32 + cg * 8) ^ ((row & 7) << 3)];
#pragma unroll
      for (int nt2 = 0; nt2 < 2; ++nt2)
        o[mt][nt2] = __builtin_amdgcn_mfma_f32_16x16x32_bf16(pa, vfr[nt2],
                                                             o[mt][nt2], 0, 0, 0);
    }
  }

  // store rows < 49, scaled by 1/rowsum
#pragma unroll
  for (int mt = 0; mt < 4; ++mt)
#pragma unroll
    for (int r = 0; r < 4; ++r) {
      int row = mt * 16 + cg * 4 + r;
      if (row < 49) {
        float ri = rinv[mt][r];
        size_t dst = (size_t)(w * 49 + row) * 256 + h * 32;
#pragma unroll
        for (int nt2 = 0; nt2 < 2; ++nt2)
          attnb[dst + nt2 * 16 + cl] = f2bf(o[mt][nt2][r] * ri);
      }
    }
}

// ---------------------------------------------------------------------------
// K3: out-proj MFMA + bias + residual + LayerNorm. BM=128, BK=32, 8 waves.
// ---------------------------------------------------------------------------
__global__ __launch_bounds__(512) void out_ln_kernel(
    const u16* __restrict__ attnb, const u16* __restrict__ woutT,
    const float* __restrict__ bout, const float* __restrict__ x,
    const float* __restrict__ gamma, const float* __restrict__ beta,
    float* __restrict__ out) {
  __shared__ __align__(16) short As[2][4096];
  __shared__ __align__(16) short Bs[2][8192];
  __shared__ float ls1[128], ls2[128];
  __shared__ int rowoff_s[128];

  int tid = threadIdx.x;
  int lane = tid & 63, wid = tid >> 6;
  int wm = wid >> 2, wn = wid & 3;
  int m0 = blockIdx.x * 128;

  if (tid < 128) {
    ls1[tid] = 0.f;
    ls2[tid] = 0.f;
    int t = m0 + tid;
    int wq = t / 49, n = t - wq * 49;
    int b = wq >> 10, rem = wq & 1023;
    int gh = (rem >> 5) * 7 + n / 7;
    int gw = (rem & 31) * 7 + n % 7;
    rowoff_s[tid] = ((b * IMG + gh) * IMG + gw) * CDIM;
  }

  f32x4 zero = {0.f, 0.f, 0.f, 0.f};
  f32x4 acc[4][4];
#pragma unroll
  for (int m = 0; m < 4; ++m)
#pragma unroll
    for (int n = 0; n < 4; ++n) acc[m][n] = zero;

#define STAGE_K3(buf, k0)                                                 \
  {                                                                       \
    {                                                                     \
      int c = tid;                                                        \
      int l6 = c & 63;                                                    \
      int rr = ((c >> 6) << 4) + (l6 & 15);                               \
      int kk = (k0) + ((l6 >> 4) << 3);                                   \
      gld_lds16(attnb + (size_t)(m0 + rr) * 256 + kk, &As[buf][c * 8]);   \
    }                                                                     \
    _Pragma("unroll") for (int i = 0; i < 2; ++i) {                       \
      int c = i * 512 + tid;                                              \
      int l6 = c & 63;                                                    \
      int cc = ((c >> 6) << 4) + (l6 & 15);                               \
      int kk = (k0) + ((l6 >> 4) << 3);                                   \
      gld_lds16(woutT + (size_t)cc * 256 + kk, &Bs[buf][c * 8]);          \
    }                                                                     \
  }

  STAGE_K3(0, 0);
  __syncthreads();

  int buf = 0;
  for (int ks = 0; ks < 8; ++ks) {
    if (ks < 7) STAGE_K3(buf ^ 1, (ks + 1) * 32);
    short8v af[4], bfv[4];
#pragma unroll
    for (int m = 0; m < 4; ++m)
      af[m] = *(const short8v*)&As[buf][((wm * 4 + m) * 64 + lane) * 8];
#pragma unroll
    for (int n = 0; n < 4; ++n)
      bfv[n] = *(const short8v*)&Bs[buf][((wn * 4 + n) * 64 + lane) * 8];
#pragma unroll
    for (int m = 0; m < 4; ++m)
#pragma unroll
      for (int n = 0; n < 4; ++n)
        acc[m][n] = __builtin_amdgcn_mfma_f32_16x16x32_bf16(af[m], bfv[n],
                                                            acc[m][n], 0, 0, 0);
    __syncthreads();
    buf ^= 1;
  }

  int fr = lane & 15, fq = lane >> 4;
#pragma unroll
  for (int m = 0; m < 4; ++m) {
#pragma unroll
    for (int r = 0; r < 4; ++r) {
      int lrow = wm * 64 + m * 16 + fq * 4 + r;
      const float* xr = x + rowoff_s[lrow];
      float s1 = 0.f, s2 = 0.f;
#pragma unroll
      for (int n = 0; n < 4; ++n) {
        int c = wn * 64 + n * 16 + fr;
        float v = acc[m][n][r] + bout[c] + xr[c];
        acc[m][n][r] = v;
        s1 += v;
        s2 += v * v;
      }
#pragma unroll
      for (int off = 1; off < 16; off <<= 1) {
        s1 += __shfl_xor(s1, off);
        s2 += __shfl_xor(s2, off);
      }
      if (fr == 0) {
        atomicAdd(&ls1[lrow], s1);
        atomicAdd(&ls2[lrow], s2);
      }
    }
  }
  __syncthreads();

#pragma unroll
  for (int m = 0; m < 4; ++m) {
#pragma unroll
    for (int r = 0; r < 4; ++r) {
      int lrow = wm * 64 + m * 16 + fq * 4 + r;
      float mean = ls1[lrow] * (1.0f / 256.0f);
      float var = ls2[lrow] * (1.0f / 256.0f) - mean * mean;
      float rstd = rsqrtf(var + LN_EPS);
      size_t orow = (size_t)(m0 + lrow) * 256;
#pragma unroll
      for (int n = 0; n < 4; ++n) {
        int c = wn * 64 + n * 16 + fr;
        out[orow + c] = (acc[m][n][r] - mean) * rstd * gamma[c] + beta[c];
      }
    }
  }
}

extern "C" void kernel_launch(void* const* d_in, const int* in_sizes, int n_in,
                              void* d_out, int out_size, void* d_ws, size_t ws_size,
                              hipStream_t stream) {
  const float* x     = (const float*)d_in[0];
  const float* wqkv  = (const float*)d_in[1];
  const float* bqkv  = (const float*)d_in[2];
  const float* btab  = (const float*)d_in[3];
  const float* wout  = (const float*)d_in[4];
  const float* bout  = (const float*)d_in[5];
  const float* gamma = (const float*)d_in[6];
  const float* beta  = (const float*)d_in[7];
  float* out = (float*)d_out;

  u16* qkvb  = (u16*)d_ws;                        // [3*8][TTOK][32] bf16 = 308 MB
  u16* xb    = qkvb + (size_t)24 * TTOK * 32;     // [TTOK][256] bf16 = 103 MB
  u16* attnb = xb;                                // reused after qkv_gemm
  u16* wqkvT = xb + (size_t)TTOK * 256;
  u16* woutT = wqkvT + 196608;

  pack_x<<<2048, 256, 0, stream>>>(x, xb);
  pack_w<<<1024, 256, 0, stream>>>(wqkv, wout, wqkvT, woutT);
  qkv_gemm<<<(TTOK / 128) * 6, 256, 0, stream>>>(xb, wqkvT, bqkv, qkvb);
  attn_kernel<<<NWIN * 2, 256, 0, stream>>>(qkvb, btab, attnb);
  out_ln_kernel<<<TTOK / 128, 512, 0, stream>>>(attnb, woutT, bout, x, gamma,
                                                beta, out);
}

// Round 4
// 922.622 us; speedup vs baseline: 2.1323x; 1.0023x over previous
//
#include <hip/hip_runtime.h>
#include <hip/hip_bf16.h>

#define BATCH 4
#define IMG 224
#define CDIM 256
#define WS 7
#define NWIN 4096
#define NTOK 49
#define TTOK 200704
#define HEADS 8
#define HD 32
#define SCALE 0.5f
#define LN_EPS 1e-5f

typedef __attribute__((ext_vector_type(8))) short short8v;
typedef __attribute__((ext_vector_type(4))) float f32x4;
typedef unsigned short u16;

__device__ __forceinline__ u16 f2bf(float f) {
  __hip_bfloat16 h = __float2bfloat16(f);
  return *reinterpret_cast<u16*>(&h);
}

__device__ __forceinline__ void gld_lds16(const void* g, void* l) {
  __builtin_amdgcn_global_load_lds(
      (const __attribute__((address_space(1))) unsigned int*)g,
      (__attribute__((address_space(3))) unsigned int*)l, 16, 0, 0);
}

// ---------------------------------------------------------------------------
// K0a: gather window-partitioned x and convert to bf16: xb[TTOK][256]
// ---------------------------------------------------------------------------
__global__ __launch_bounds__(256) void pack_x(const float* __restrict__ x,
                                              u16* __restrict__ xb) {
  const int NCH = TTOK * 32;  // 8-elem chunks
  for (int id = blockIdx.x * 256 + threadIdx.x; id < NCH; id += 2048 * 256) {
    int t = id >> 5;
    int cc = (id & 31) << 3;
    int wq = t / 49, n = t - wq * 49;
    int b = wq >> 10, rem = wq & 1023;
    int gh = (rem >> 5) * 7 + n / 7;
    int gw = (rem & 31) * 7 + n % 7;
    const float* src = x + (((size_t)b * IMG + gh) * IMG + gw) * CDIM + cc;
    float4 f0 = *(const float4*)src;
    float4 f1 = *(const float4*)(src + 4);
    union { u16 us[8]; uint4 v; } pk;
    pk.us[0] = f2bf(f0.x); pk.us[1] = f2bf(f0.y);
    pk.us[2] = f2bf(f0.z); pk.us[3] = f2bf(f0.w);
    pk.us[4] = f2bf(f1.x); pk.us[5] = f2bf(f1.y);
    pk.us[6] = f2bf(f1.z); pk.us[7] = f2bf(f1.w);
    *(uint4*)(xb + (size_t)id * 8) = pk.v;
  }
}

// ---------------------------------------------------------------------------
// K0b: transpose+convert weights to N-major bf16: wqkvT[n][k], woutT[n][k]
// ---------------------------------------------------------------------------
__global__ __launch_bounds__(256) void pack_w(const float* __restrict__ wqkv,
                                              const float* __restrict__ wout,
                                              u16* __restrict__ wqkvT,
                                              u16* __restrict__ woutT) {
  int id = blockIdx.x * 256 + threadIdx.x;  // 262144
  if (id < 196608) {
    int nn = id >> 8, k = id & 255;
    wqkvT[id] = f2bf(wqkv[(size_t)k * 768 + nn]);
  } else {
    int id2 = id - 196608;
    int nn = id2 >> 8, k = id2 & 255;
    woutT[id2] = f2bf(wout[(size_t)k * 256 + nn]);
  }
}

// ---------------------------------------------------------------------------
// K1: QKV GEMM, bf16 MFMA, 128x128 tile, BK=32, double-buffered
// global_load_lds. XCD-swizzled blockIdx: the 6 N-tiles sharing an A-tile
// run consecutively on ONE XCD -> A fetched ~once from HBM (was 3x).
// Output: bf16, planes [which][head][t][32].
// ---------------------------------------------------------------------------
__global__ __launch_bounds__(256) void qkv_gemm(const u16* __restrict__ xb,
                                                const u16* __restrict__ wqkvT,
                                                const float* __restrict__ bqkv,
                                                u16* __restrict__ qkvb) {
  __shared__ __align__(16) short As[2][4096];
  __shared__ __align__(16) short Bs[2][4096];

  int tid = threadIdx.x;
  int lane = tid & 63, wid = tid >> 6;
  int wm = wid >> 1, wn = wid & 1;
  // grid = 9408 = 8 * 1176; bijective XCD swizzle (nwg % 8 == 0)
  int hb = blockIdx.x;
  int bid = (hb & 7) * 1176 + (hb >> 3);
  int mt = bid / 6, nt = bid % 6;
  int m0 = mt * 128, n0 = nt * 128;

  f32x4 zero = {0.f, 0.f, 0.f, 0.f};
  f32x4 acc[4][4];
#pragma unroll
  for (int m = 0; m < 4; ++m)
#pragma unroll
    for (int n = 0; n < 4; ++n) acc[m][n] = zero;

#define STAGE_K1(buf, k0)                                                \
  {                                                                      \
    _Pragma("unroll") for (int i = 0; i < 2; ++i) {                      \
      int c = i * 256 + tid;                                             \
      int l6 = c & 63;                                                   \
      int rr = ((c >> 6) << 4) + (l6 & 15);                              \
      int kk = (k0) + ((l6 >> 4) << 3);                                  \
      gld_lds16(xb + (size_t)(m0 + rr) * 256 + kk, &As[buf][c * 8]);     \
      gld_lds16(wqkvT + (size_t)(n0 + rr) * 256 + kk, &Bs[buf][c * 8]);  \
    }                                                                    \
  }

  STAGE_K1(0, 0);
  __syncthreads();

  int buf = 0;
  for (int ks = 0; ks < 8; ++ks) {
    if (ks < 7) STAGE_K1(buf ^ 1, (ks + 1) * 32);
    short8v af[4], bfv[4];
#pragma unroll
    for (int m = 0; m < 4; ++m)
      af[m] = *(const short8v*)&As[buf][((wm * 4 + m) * 64 + lane) * 8];
#pragma unroll
    for (int n = 0; n < 4; ++n)
      bfv[n] = *(const short8v*)&Bs[buf][((wn * 4 + n) * 64 + lane) * 8];
#pragma unroll
    for (int m = 0; m < 4; ++m)
#pragma unroll
      for (int n = 0; n < 4; ++n)
        acc[m][n] = __builtin_amdgcn_mfma_f32_16x16x32_bf16(af[m], bfv[n],
                                                            acc[m][n], 0, 0, 0);
    __syncthreads();
    buf ^= 1;
  }

  // epilogue: bias + bf16 scatter to [which*8+head][t][d]
  int fr = lane & 15, fq = lane >> 4;
#pragma unroll
  for (int n = 0; n < 4; ++n) {
    int c = n0 + wn * 64 + n * 16 + fr;
    float bias = bqkv[c];
    u16* plane = qkvb + (size_t)((c >> 8) * 8 + ((c >> 5) & 7)) * TTOK * 32;
    int d = c & 31;
#pragma unroll
    for (int m = 0; m < 4; ++m) {
      int t0 = m0 + wm * 64 + m * 16 + fq * 4;
#pragma unroll
      for (int r = 0; r < 4; ++r)
        plane[(size_t)(t0 + r) * 32 + d] = f2bf(acc[m][n][r] + bias);
    }
  }
}

// ---------------------------------------------------------------------------
// K2: MFMA attention. One wave per (window, head); 4 waves/block.
// Q/K frags direct from global; V transposed into LDS; P via LDS (swizzled).
// Cols >= 49 masked to -1e30. Writes attnb bf16 [t][256].
// ---------------------------------------------------------------------------
__global__ __launch_bounds__(256) void attn_kernel(
    const u16* __restrict__ qkvb, const float* __restrict__ bias_table,
    u16* __restrict__ attnb) {
  __shared__ u16 Pl[4][4096];       // 64x64 bf16, XOR-swizzled
  __shared__ u16 Vl[4][32 * 72];    // V^T: [d][k], stride 72
  __shared__ float bsh[4][169];

  int bid = blockIdx.x;  // NWIN*2
  int w = bid >> 1;
  int wid = threadIdx.x >> 6, lane = threadIdx.x & 63;
  int h = ((bid & 1) << 2) | wid;
  int cl = lane & 15, cg = lane >> 4;

  for (int i = lane; i < 169; i += 64)
    bsh[wid][i] = bias_table[i * HEADS + h];

  const size_t wbase = (size_t)w * 49 * 32;
  const u16* qp = qkvb + (size_t)h * TTOK * 32 + wbase;
  const u16* kp = qkvb + (size_t)(8 + h) * TTOK * 32 + wbase;
  const u16* vp = qkvb + (size_t)(16 + h) * TTOK * 32 + wbase;

  // Q/K fragments (A-frag layout: row = lane&15, k = (lane>>4)*8 + j)
  short8v qf[4], kf[4];
#pragma unroll
  for (int mt = 0; mt < 4; ++mt) {
    int off = (mt * 16 + cl) * 32 + cg * 8;
    qf[mt] = *(const short8v*)(qp + off);
    kf[mt] = *(const short8v*)(kp + off);
  }

  // stage V transposed into LDS: Vl[d][k], zero-fill k >= 49
  short8v vz = {0, 0, 0, 0, 0, 0, 0, 0};
#pragma unroll
  for (int pass = 0; pass < 4; ++pass) {
    int cidx = pass * 64 + lane;
    int t = cidx >> 2, dc = (cidx & 3) * 8;
    short8v vv = (t < 49) ? *(const short8v*)(vp + t * 32 + dc) : vz;
#pragma unroll
    for (int j = 0; j < 8; ++j) Vl[wid][(dc + j) * 72 + t] = vv[j];
  }

  // S = Q K^T  (16 MFMAs, K=32 = full head dim)
  f32x4 zero4 = {0.f, 0.f, 0.f, 0.f};
  f32x4 s[4][4];
#pragma unroll
  for (int mt = 0; mt < 4; ++mt)
#pragma unroll
    for (int nt = 0; nt < 4; ++nt)
      s[mt][nt] = __builtin_amdgcn_mfma_f32_16x16x32_bf16(qf[mt], kf[nt],
                                                          zero4, 0, 0, 0);

  // key-side bias decomposition (col = nt*16 + cl)
  int kr7[4], kc7[4];
#pragma unroll
  for (int nt = 0; nt < 4; ++nt) {
    int col = nt * 16 + cl;
    kr7[nt] = (col * 9363) >> 16;
    kc7[nt] = col - kr7[nt] * 7;
  }

  // bias + scale + mask, then softmax per row (C-layout: row=(cg)*4+r)
  f32x4 rinv[4];
#pragma unroll
  for (int mt = 0; mt < 4; ++mt) {
#pragma unroll
    for (int r = 0; r < 4; ++r) {
      int row = mt * 16 + cg * 4 + r;
      int qr = (row * 9363) >> 16;
      int qc = row - qr * 7;
      float sv[4];
#pragma unroll
      for (int nt = 0; nt < 4; ++nt) {
        int col = nt * 16 + cl;
        if (col < 49) {
          int idx = (qr - kr7[nt] + 6) * 13 + (qc - kc7[nt] + 6);
          sv[nt] = s[mt][nt][r] * SCALE + bsh[wid][idx];
        } else {
          sv[nt] = -1e30f;
        }
      }
      float m = fmaxf(fmaxf(sv[0], sv[1]), fmaxf(sv[2], sv[3]));
#pragma unroll
      for (int msk = 1; msk < 16; msk <<= 1) m = fmaxf(m, __shfl_xor(m, msk));
      float sum = 0.f;
#pragma unroll
      for (int nt = 0; nt < 4; ++nt) {
        float p = __expf(sv[nt] - m);
        s[mt][nt][r] = p;
        sum += p;
      }
#pragma unroll
      for (int msk = 1; msk < 16; msk <<= 1) sum += __shfl_xor(sum, msk);
      rinv[mt][r] = 1.0f / sum;
    }
  }

  // write P (bf16) to LDS, XOR-swizzled on element index
#pragma unroll
  for (int mt = 0; mt < 4; ++mt)
#pragma unroll
    for (int r = 0; r < 4; ++r) {
      int row = mt * 16 + cg * 4 + r;
      int swz = (row & 7) << 3;
#pragma unroll
      for (int nt = 0; nt < 4; ++nt) {
        int col = nt * 16 + cl;
        Pl[wid][(row * 64 + col) ^ swz] = f2bf(s[mt][nt][r]);
      }
    }

  // O = P V   (A = P from LDS, B = V^T rows from LDS)
  f32x4 o[4][2];
#pragma unroll
  for (int mt = 0; mt < 4; ++mt)
#pragma unroll
    for (int nt2 = 0; nt2 < 2; ++nt2) o[mt][nt2] = zero4;

#pragma unroll
  for (int kt = 0; kt < 2; ++kt) {
    short8v vfr[2];
#pragma unroll
    for (int nt2 = 0; nt2 < 2; ++nt2)
      vfr[nt2] = *(const short8v*)&Vl[wid][(nt2 * 16 + cl) * 72 + kt * 32 + cg * 8];
#pragma unroll
    for (int mt = 0; mt < 4; ++mt) {
      int row = mt * 16 + cl;
      short8v pa = *(const short8v*)
          &Pl[wid][(row * 64 + kt * 32 + cg * 8) ^ ((row & 7) << 3)];
#pragma unroll
      for (int nt2 = 0; nt2 < 2; ++nt2)
        o[mt][nt2] = __builtin_amdgcn_mfma_f32_16x16x32_bf16(pa, vfr[nt2],
                                                             o[mt][nt2], 0, 0, 0);
    }
  }

  // store rows < 49, scaled by 1/rowsum
#pragma unroll
  for (int mt = 0; mt < 4; ++mt)
#pragma unroll
    for (int r = 0; r < 4; ++r) {
      int row = mt * 16 + cg * 4 + r;
      if (row < 49) {
        float ri = rinv[mt][r];
        size_t dst = (size_t)(w * 49 + row) * 256 + h * 32;
#pragma unroll
        for (int nt2 = 0; nt2 < 2; ++nt2)
          attnb[dst + nt2 * 16 + cl] = f2bf(o[mt][nt2][r] * ri);
      }
    }
}

// ---------------------------------------------------------------------------
// K3: out-proj MFMA + bias + residual + LayerNorm. BM=128, BK=32, 8 waves.
// ---------------------------------------------------------------------------
__global__ __launch_bounds__(512) void out_ln_kernel(
    const u16* __restrict__ attnb, const u16* __restrict__ woutT,
    const float* __restrict__ bout, const float* __restrict__ x,
    const float* __restrict__ gamma, const float* __restrict__ beta,
    float* __restrict__ out) {
  __shared__ __align__(16) short As[2][4096];
  __shared__ __align__(16) short Bs[2][8192];
  __shared__ float ls1[128], ls2[128];
  __shared__ int rowoff_s[128];

  int tid = threadIdx.x;
  int lane = tid & 63, wid = tid >> 6;
  int wm = wid >> 2, wn = wid & 3;
  int m0 = blockIdx.x * 128;

  if (tid < 128) {
    ls1[tid] = 0.f;
    ls2[tid] = 0.f;
    int t = m0 + tid;
    int wq = t / 49, n = t - wq * 49;
    int b = wq >> 10, rem = wq & 1023;
    int gh = (rem >> 5) * 7 + n / 7;
    int gw = (rem & 31) * 7 + n % 7;
    rowoff_s[tid] = ((b * IMG + gh) * IMG + gw) * CDIM;
  }

  f32x4 zero = {0.f, 0.f, 0.f, 0.f};
  f32x4 acc[4][4];
#pragma unroll
  for (int m = 0; m < 4; ++m)
#pragma unroll
    for (int n = 0; n < 4; ++n) acc[m][n] = zero;

#define STAGE_K3(buf, k0)                                                 \
  {                                                                       \
    {                                                                     \
      int c = tid;                                                        \
      int l6 = c & 63;                                                    \
      int rr = ((c >> 6) << 4) + (l6 & 15);                               \
      int kk = (k0) + ((l6 >> 4) << 3);                                   \
      gld_lds16(attnb + (size_t)(m0 + rr) * 256 + kk, &As[buf][c * 8]);   \
    }                                                                     \
    _Pragma("unroll") for (int i = 0; i < 2; ++i) {                       \
      int c = i * 512 + tid;                                              \
      int l6 = c & 63;                                                    \
      int cc = ((c >> 6) << 4) + (l6 & 15);                               \
      int kk = (k0) + ((l6 >> 4) << 3);                                   \
      gld_lds16(woutT + (size_t)cc * 256 + kk, &Bs[buf][c * 8]);          \
    }                                                                     \
  }

  STAGE_K3(0, 0);
  __syncthreads();

  int buf = 0;
  for (int ks = 0; ks < 8; ++ks) {
    if (ks < 7) STAGE_K3(buf ^ 1, (ks + 1) * 32);
    short8v af[4], bfv[4];
#pragma unroll
    for (int m = 0; m < 4; ++m)
      af[m] = *(const short8v*)&As[buf][((wm * 4 + m) * 64 + lane) * 8];
#pragma unroll
    for (int n = 0; n < 4; ++n)
      bfv[n] = *(const short8v*)&Bs[buf][((wn * 4 + n) * 64 + lane) * 8];
#pragma unroll
    for (int m = 0; m < 4; ++m)
#pragma unroll
      for (int n = 0; n < 4; ++n)
        acc[m][n] = __builtin_amdgcn_mfma_f32_16x16x32_bf16(af[m], bfv[n],
                                                            acc[m][n], 0, 0, 0);
    __syncthreads();
    buf ^= 1;
  }

  int fr = lane & 15, fq = lane >> 4;
#pragma unroll
  for (int m = 0; m < 4; ++m) {
#pragma unroll
    for (int r = 0; r < 4; ++r) {
      int lrow = wm * 64 + m * 16 + fq * 4 + r;
      const float* xr = x + rowoff_s[lrow];
      float s1 = 0.f, s2 = 0.f;
#pragma unroll
      for (int n = 0; n < 4; ++n) {
        int c = wn * 64 + n * 16 + fr;
        float v = acc[m][n][r] + bout[c] + xr[c];
        acc[m][n][r] = v;
        s1 += v;
        s2 += v * v;
      }
#pragma unroll
      for (int off = 1; off < 16; off <<= 1) {
        s1 += __shfl_xor(s1, off);
        s2 += __shfl_xor(s2, off);
      }
      if (fr == 0) {
        atomicAdd(&ls1[lrow], s1);
        atomicAdd(&ls2[lrow], s2);
      }
    }
  }
  __syncthreads();

#pragma unroll
  for (int m = 0; m < 4; ++m) {
#pragma unroll
    for (int r = 0; r < 4; ++r) {
      int lrow = wm * 64 + m * 16 + fq * 4 + r;
      float mean = ls1[lrow] * (1.0f / 256.0f);
      float var = ls2[lrow] * (1.0f / 256.0f) - mean * mean;
      float rstd = rsqrtf(var + LN_EPS);
      size_t orow = (size_t)(m0 + lrow) * 256;
#pragma unroll
      for (int n = 0; n < 4; ++n) {
        int c = wn * 64 + n * 16 + fr;
        out[orow + c] = (acc[m][n][r] - mean) * rstd * gamma[c] + beta[c];
      }
    }
  }
}

extern "C" void kernel_launch(void* const* d_in, const int* in_sizes, int n_in,
                              void* d_out, int out_size, void* d_ws, size_t ws_size,
                              hipStream_t stream) {
  const float* x     = (const float*)d_in[0];
  const float* wqkv  = (const float*)d_in[1];
  const float* bqkv  = (const float*)d_in[2];
  const float* btab  = (const float*)d_in[3];
  const float* wout  = (const float*)d_in[4];
  const float* bout  = (const float*)d_in[5];
  const float* gamma = (const float*)d_in[6];
  const float* beta  = (const float*)d_in[7];
  float* out = (float*)d_out;

  u16* qkvb  = (u16*)d_ws;                        // [3*8][TTOK][32] bf16 = 308 MB
  u16* xb    = qkvb + (size_t)24 * TTOK * 32;     // [TTOK][256] bf16 = 103 MB
  u16* attnb = xb;                                // reused after qkv_gemm
  u16* wqkvT = xb + (size_t)TTOK * 256;
  u16* woutT = wqkvT + 196608;

  pack_x<<<2048, 256, 0, stream>>>(x, xb);
  pack_w<<<1024, 256, 0, stream>>>(wqkv, wout, wqkvT, woutT);
  qkv_gemm<<<(TTOK / 128) * 6, 256, 0, stream>>>(xb, wqkvT, bqkv, qkvb);
  attn_kernel<<<NWIN * 2, 256, 0, stream>>>(qkvb, btab, attnb);
  out_ln_kernel<<<TTOK / 128, 512, 0, stream>>>(attnb, woutT, bout, x, gamma,
                                                beta, out);
}